// Round 4
// baseline (290.908 us; speedup 1.0000x reference)
//
#include <hip/hip_runtime.h>

#define N_NODES 8192
#define DIM 32
#define NCLS 16
#define SPLITK 8
#define KSEG (N_NODES / SPLITK) /* 1024 */
#define NCOLC 36                /* packed partial-C columns (cols 36..47 structurally zero) */

typedef __bf16 bf16x8 __attribute__((ext_vector_type(8)));
typedef float f32x4 __attribute__((ext_vector_type(4)));

__device__ inline unsigned short f2bf(float f) {
  unsigned u = __float_as_uint(f);
  u = u + 0x7FFFu + ((u >> 16) & 1u);  // round-to-nearest-even
  return (unsigned short)(u >> 16);
}

__device__ inline float artanh_pos(float x) {  // x >= 0, clipped like jnp reference
  x = fminf(x, 1.0f - 1e-7f);
  return 0.5f * logf((1.0f + x) / (1.0f - x));
}

__device__ inline bf16x8 cvt8(f32x4 lo, f32x4 hi) {
  bf16x8 r;
  r[0] = (__bf16)lo[0]; r[1] = (__bf16)lo[1]; r[2] = (__bf16)lo[2]; r[3] = (__bf16)lo[3];
  r[4] = (__bf16)hi[0]; r[5] = (__bf16)hi[1]; r[6] = (__bf16)hi[2]; r[7] = (__bf16)hi[3];
  return r;
}

// async global->LDS, 16B per lane; LDS dest = wave-uniform base + lane*16 (HW rule)
__device__ inline void gll16(const void* g, const void* l) {
  __builtin_amdgcn_global_load_lds(
      (const __attribute__((address_space(1))) unsigned int*)(unsigned long long)g,
      (__attribute__((address_space(3))) unsigned int*)(unsigned int)(unsigned long long)l,
      16, 0, 0);
}

// ---------------- pre: mobius_matvec + gamma -> G^T bf16 [48][N] ----------------
__device__ inline void pre_math(const float* __restrict__ Wl, const float x[DIM],
                                unsigned short* __restrict__ GT, int n) {
  float xn2 = 0.f;
#pragma unroll
  for (int i = 0; i < DIM; i++) xn2 += x[i] * x[i];
  float xn = sqrtf(fmaxf(xn2, 1e-30f));
  float mx[DIM];
#pragma unroll
  for (int j = 0; j < DIM; j++) mx[j] = 0.f;
  for (int i = 0; i < DIM; i++) {
    float xi = x[i];
#pragma unroll
    for (int j = 0; j < DIM; j++) mx[j] = fmaf(xi, Wl[i * DIM + j], mx[j]);
  }
  float mxn2 = 0.f;
#pragma unroll
  for (int j = 0; j < DIM; j++) mxn2 += mx[j] * mx[j];
  float mxn = sqrtf(fmaxf(mxn2, 1e-30f));
  float t = tanhf(mxn / xn * artanh_pos(xn));
  float sc = t / mxn;
  float xw[DIM];
  float x2n = 0.f;
#pragma unroll
  for (int j = 0; j < DIM; j++) { xw[j] = sc * mx[j]; x2n += xw[j] * xw[j]; }
  float gamma = 2.0f / fmaxf(1.0f - x2n, 1e-15f);
#pragma unroll
  for (int c = 0; c < DIM; c++) GT[(size_t)c * N_NODES + n] = f2bf(gamma * xw[c]);
  GT[(size_t)DIM * N_NODES + n] = f2bf(gamma - 1.0f);
  GT[(size_t)(DIM + 1) * N_NODES + n] = f2bf(1.0f);
#pragma unroll
  for (int c = DIM + 2; c < 48; c++) GT[(size_t)c * N_NODES + n] = 0;
}

__global__ void k_pre1(const float* __restrict__ X, const float* __restrict__ W,
                       unsigned short* __restrict__ GT) {
  __shared__ float Wl[DIM * DIM];
  for (int i = threadIdx.x; i < DIM * DIM; i += blockDim.x) Wl[i] = W[i];
  __syncthreads();
  const int n = blockIdx.x * blockDim.x + threadIdx.x;
  float x[DIM];
#pragma unroll
  for (int i = 0; i < DIM; i += 4) {
    float4 v = *(const float4*)(X + (size_t)n * DIM + i);
    x[i] = v.x; x[i + 1] = v.y; x[i + 2] = v.z; x[i + 3] = v.w;
  }
  pre_math(Wl, x, GT, n);
}

// ---------------- post math: reads reduced C [N][36] ----------------
__device__ inline void post_math(const float* __restrict__ Cred, int n, float xo[DIM]) {
  float acc[36];
  const float4* p = (const float4*)(Cred + (size_t)n * NCOLC);
#pragma unroll
  for (int q = 0; q < 9; q++) {
    float4 v = p[q];
    acc[q * 4 + 0] = v.x; acc[q * 4 + 1] = v.y;
    acc[q * 4 + 2] = v.z; acc[q * 4 + 3] = v.w;
  }
  float denom = acc[32];
  float alpha = acc[33];
  denom = (denom >= 0.f) ? fmaxf(denom, 1e-10f) : fminf(denom, -1e-10f);
  float inv = 1.0f / denom;
  float v[DIM];
  float vn2 = 0.f;
#pragma unroll
  for (int c = 0; c < DIM; c++) { v[c] = acc[c] * inv; vn2 += v[c] * v[c]; }
  float vn = sqrtf(fmaxf(vn2, 1e-30f));
  float un = alpha * 0.5f * artanh_pos(vn);
  float su = un / vn;
  float r[DIM];
  float rn2 = 0.f;
#pragma unroll
  for (int c = 0; c < DIM; c++) { r[c] = fmaxf(su * v[c], 0.f); rn2 += r[c] * r[c]; }
  float rn = sqrtf(fmaxf(rn2, 1e-30f));
  float so = tanhf(rn) / rn;
#pragma unroll
  for (int c = 0; c < DIM; c++) xo[c] = so * r[c];
}

__global__ void k_postpre(const float* __restrict__ Cred, const float* __restrict__ W,
                          unsigned short* __restrict__ GT) {
  __shared__ float Wl[DIM * DIM];
  for (int i = threadIdx.x; i < DIM * DIM; i += blockDim.x) Wl[i] = W[i];
  __syncthreads();
  const int n = blockIdx.x * blockDim.x + threadIdx.x;
  float x[DIM];
  post_math(Cred, n, x);
  pre_math(Wl, x, GT, n);
}

__global__ void k_postlogits(const float* __restrict__ Cred, const float* __restrict__ Wl_g,
                             const float* __restrict__ B_g, unsigned short* __restrict__ LT) {
  __shared__ float Wc[DIM * NCLS];
  __shared__ float Bc[NCLS * DIM];
  __shared__ float an_s[NCLS], lam_s[NCLS], b2_s[NCLS];
  for (int i = threadIdx.x; i < DIM * NCLS; i += blockDim.x) { Wc[i] = Wl_g[i]; Bc[i] = B_g[i]; }
  __syncthreads();
  if (threadIdx.x < NCLS) {
    int c = threadIdx.x;
    float b2 = 0.f, w2 = 0.f;
    for (int d = 0; d < DIM; d++) {
      b2 += Bc[c * DIM + d] * Bc[c * DIM + d];
      w2 += Wc[d * NCLS + c] * Wc[d * NCLS + c];
    }
    b2_s[c] = b2;
    an_s[c] = fmaxf(sqrtf(w2), 1e-10f);
    lam_s[c] = 2.0f / fmaxf(1.0f - b2, 1e-15f);
  }
  __syncthreads();
  const int n = blockIdx.x * blockDim.x + threadIdx.x;
  float x[DIM];
  post_math(Cred, n, x);
  float y2 = 0.f;
#pragma unroll
  for (int i = 0; i < DIM; i++) y2 += x[i] * x[i];
  for (int c = 0; c < NCLS; c++) {
    float b2 = b2_s[c];
    float bx = 0.f;
    for (int d = 0; d < DIM; d++) bx += Bc[c * DIM + d] * x[d];
    float xy = -bx;
    float f1 = 1.0f + 2.0f * xy + y2;
    float f2 = 1.0f - b2;
    float den = fmaxf(1.0f + 2.0f * xy + b2 * y2, 1e-15f);
    float invden = 1.0f / den;
    float zn2 = 0.f, za = 0.f;
    for (int d = 0; d < DIM; d++) {
      float z = (f1 * (-Bc[c * DIM + d]) + f2 * x[d]) * invden;
      zn2 += z * z;
      za += z * Wc[d * NCLS + c];
    }
    float zn = fmaxf(sqrtf(fmaxf(zn2, 1e-30f)), 1e-10f);
    float dist = asinhf(2.0f * za / ((1.0f - zn * zn) * an_s[c]));
    LT[(size_t)c * N_NODES + n] = f2bf(lam_s[c] * an_s[c] * dist);
  }
}

// ---------------- MFMA matmul, bf16 A, LDS row-volley staging ----------------
// 4 waves x 16 rows, each wave independent (no barriers). One gll16 volley = one
// full 1KB row segment -> HBM page-friendly. XOR chunk swizzle (c ^ (row&7)) applied
// to the *global source* (LDS dest linear), undone on ds_read -> conflict-free.
template <int NF>
__global__ __launch_bounds__(256) void k_mm(const unsigned short* __restrict__ A,
                                            const unsigned short* __restrict__ BT,
                                            float* __restrict__ Cpart) {
  __shared__ __align__(16) unsigned short sm[64 * 512];  // 64 KB
  const int lane = threadIdx.x & 63;
  const int wid = threadIdx.x >> 6;
  const int rb = blockIdx.x * 64 + wid * 16;  // wave's first row
  const int k0 = blockIdx.y * KSEG;
  const int lr = lane & 15;
  const int lkg = lane >> 4;
  const int m8 = lr & 7;
  unsigned short* smw = sm + wid * 16 * 512;

  f32x4 acc[NF];
#pragma unroll
  for (int nf = 0; nf < NF; nf++) acc[nf] = (f32x4){0.f, 0.f, 0.f, 0.f};
  const unsigned short* pb[NF];
#pragma unroll
  for (int nf = 0; nf < NF; nf++) pb[nf] = BT + (size_t)(nf * 16 + lr) * N_NODES + k0 + lkg * 8;
  const unsigned short* arow = smw + lr * 512;

#pragma unroll 1
  for (int s = 0; s < KSEG / 512; s++) {
    const unsigned short* gbase = A + (size_t)rb * N_NODES + k0 + s * 512;
#pragma unroll
    for (int j = 0; j < 16; j++)  // one volley = one row's 1KB, chunks pre-swizzled
      gll16(gbase + (size_t)j * N_NODES + ((lane ^ (j & 7)) * 8), smw + j * 512);
    asm volatile("s_waitcnt vmcnt(0)" ::: "memory");
#pragma unroll
    for (int kk = 0; kk < 512; kk += 32) {
      const int ch = kk / 8 + lkg;
      bf16x8 a = *(const bf16x8*)(arow + ((ch ^ m8) * 8));
#pragma unroll
      for (int nf = 0; nf < NF; nf++) {
        bf16x8 b = *(const bf16x8*)(pb[nf] + s * 512 + kk);
        acc[nf] = __builtin_amdgcn_mfma_f32_16x16x32_bf16(a, b, acc[nf], 0, 0, 0);
      }
    }
  }
  const int NCOL = (NF == 3) ? NCOLC : NF * 16;
  float* Cb = Cpart + (size_t)blockIdx.y * N_NODES * NCOL;
#pragma unroll
  for (int nf = 0; nf < NF; nf++) {
    if (NF == 3 && nf == 2 && lr >= 4) continue;  // cols 36..47 never read
#pragma unroll
    for (int j = 0; j < 4; j++)
      Cb[(size_t)(rb + lkg * 4 + j) * NCOL + nf * 16 + lr] = acc[nf][j];
  }
}

// ---------------- pass 1: fp32 A staged, convert in-register, emit Abf contiguously ----------------
__global__ __launch_bounds__(256) void k_mmc(const float* __restrict__ A,
                                             const unsigned short* __restrict__ BT,
                                             float* __restrict__ Cpart,
                                             unsigned short* __restrict__ Abf) {
  __shared__ __align__(16) float smf[64 * 256];  // 64 KB
  const int lane = threadIdx.x & 63;
  const int wid = threadIdx.x >> 6;
  const int rb = blockIdx.x * 64 + wid * 16;
  const int k0 = blockIdx.y * KSEG;
  const int lr = lane & 15;
  const int lkg = lane >> 4;
  const int m8 = lr & 7;
  float* smw = smf + wid * 16 * 256;

  f32x4 acc[3];
#pragma unroll
  for (int nf = 0; nf < 3; nf++) acc[nf] = (f32x4){0.f, 0.f, 0.f, 0.f};
  const unsigned short* pb[3];
#pragma unroll
  for (int nf = 0; nf < 3; nf++) pb[nf] = BT + (size_t)(nf * 16 + lr) * N_NODES + k0 + lkg * 8;

#pragma unroll 1
  for (int s = 0; s < KSEG / 256; s++) {
    const float* gbase = A + (size_t)rb * N_NODES + k0 + s * 256;
#pragma unroll
    for (int j = 0; j < 16; j++)  // one volley = one row's 1KB fp32
      gll16(gbase + (size_t)j * N_NODES + ((lane ^ (j & 7)) * 4), smw + j * 256);
    asm volatile("s_waitcnt vmcnt(0)" ::: "memory");
    // MFMA over this K-slab
#pragma unroll
    for (int kk = 0; kk < 256; kk += 32) {
      const int c0 = kk / 4 + lkg * 2;  // even
      f32x4 lo = *(const f32x4*)(smw + lr * 256 + ((c0 ^ m8) * 4));
      f32x4 hi = *(const f32x4*)(smw + lr * 256 + (((c0 + 1) ^ m8) * 4));
      bf16x8 a = cvt8(lo, hi);
#pragma unroll
      for (int nf = 0; nf < 3; nf++) {
        bf16x8 b = *(const bf16x8*)(pb[nf] + s * 256 + kk);
        acc[nf] = __builtin_amdgcn_mfma_f32_16x16x32_bf16(a, b, acc[nf], 0, 0, 0);
      }
    }
    // convert-store pass: contiguous 512B-per-row bf16 stores (2 rows per volley)
#pragma unroll
    for (int v = 0; v < 8; v++) {
      const int rv = v * 2 + (lane >> 5);
      const int mv = rv & 7;
      const int oc = lane & 31;
      f32x4 lo = *(const f32x4*)(smw + rv * 256 + (((2 * oc) ^ mv) * 4));
      f32x4 hi = *(const f32x4*)(smw + rv * 256 + (((2 * oc + 1) ^ mv) * 4));
      bf16x8 o = cvt8(lo, hi);
      *(bf16x8*)(Abf + (size_t)(rb + rv) * N_NODES + k0 + s * 256 + oc * 8) = o;
    }
  }
  float* Cb = Cpart + (size_t)blockIdx.y * N_NODES * NCOLC;
#pragma unroll
  for (int nf = 0; nf < 3; nf++) {
    if (nf == 2 && lr >= 4) continue;
#pragma unroll
    for (int j = 0; j < 4; j++)
      Cb[(size_t)(rb + lkg * 4 + j) * NCOLC + nf * 16 + lr] = acc[nf][j];
  }
}

// ---------------- splitK reduce (contiguous) ----------------
template <int TOTAL>
__global__ void k_red(const float* __restrict__ part, float* __restrict__ outb) {
  int i = blockIdx.x * blockDim.x + threadIdx.x;
  if (i < TOTAL) {
    float s = 0.f;
#pragma unroll
    for (int q = 0; q < SPLITK; q++) s += part[(size_t)q * TOTAL + i];
    outb[i] = s;
  }
}

extern "C" void kernel_launch(void* const* d_in, const int* in_sizes, int n_in,
                              void* d_out, int out_size, void* d_ws, size_t ws_size,
                              hipStream_t stream) {
  (void)in_sizes; (void)n_in; (void)out_size; (void)ws_size;
  const float* X  = (const float*)d_in[0];
  const float* A  = (const float*)d_in[1];
  const float* W1 = (const float*)d_in[2];
  const float* W2 = (const float*)d_in[3];
  const float* WL = (const float*)d_in[4];
  const float* PK = (const float*)d_in[5];
  float* out = (float*)d_out;

  char* ws = (char*)d_ws;
  unsigned short* Abf = (unsigned short*)ws;                  // 134,217,728 B
  unsigned short* GT  = (unsigned short*)(ws + 134217728);    //     786,432 B
  float* Cpart        = (float*)(ws + 135004160);             //   9,437,184 B
  float* Cred         = (float*)(ws + 144441344);             //   1,179,648 B
  unsigned short* LT  = (unsigned short*)(ws + 145620992);    //     262,144 B

  // layer 1 (A fp32 read + bf16 convert fused into pass 1)
  k_pre1<<<N_NODES / 64, 64, 0, stream>>>(X, W1, GT);
  k_mmc<<<dim3(128, SPLITK), 256, 0, stream>>>(A, GT, Cpart, Abf);
  k_red<N_NODES * NCOLC><<<N_NODES * NCOLC / 256, 256, 0, stream>>>(Cpart, Cred);
  k_postpre<<<N_NODES / 64, 64, 0, stream>>>(Cred, W2, GT);

  // layer 2
  k_mm<3><<<dim3(128, SPLITK), 256, 0, stream>>>(Abf, GT, Cpart);
  k_red<N_NODES * NCOLC><<<N_NODES * NCOLC / 256, 256, 0, stream>>>(Cpart, Cred);
  k_postlogits<<<N_NODES / 64, 64, 0, stream>>>(Cred, WL, PK, LT);

  // logits aggregation
  k_mm<1><<<dim3(128, SPLITK), 256, 0, stream>>>(Abf, LT, Cpart);
  k_red<N_NODES * NCLS><<<N_NODES * NCLS / 256, 256, 0, stream>>>(Cpart, out);
}

// Round 5
// 256.081 us; speedup vs baseline: 1.1360x; 1.1360x over previous
//
#include <hip/hip_runtime.h>

#define N_NODES 8192
#define DIM 32
#define NCLS 16
#define SPLITK 16
#define KSEG (N_NODES / SPLITK) /* 512 */
#define NCOLC 36                /* packed partial-C columns (cols 36..47 structurally zero) */

typedef __bf16 bf16x8 __attribute__((ext_vector_type(8)));
typedef float f32x4 __attribute__((ext_vector_type(4)));

__device__ inline unsigned short f2bf(float f) {
  unsigned u = __float_as_uint(f);
  u = u + 0x7FFFu + ((u >> 16) & 1u);  // round-to-nearest-even
  return (unsigned short)(u >> 16);
}

__device__ inline float artanh_pos(float x) {  // x >= 0, clipped like jnp reference
  x = fminf(x, 1.0f - 1e-7f);
  return 0.5f * logf((1.0f + x) / (1.0f - x));
}

// ---------------- A fp32 -> bf16 (RNE), every instruction lane-dense ----------------
// Per iter per lane: two dense float4 loads (wave covers 2x1KB contiguous),
// two dense 8B stores (wave covers 2x512B contiguous).
__global__ __launch_bounds__(256) void k_convert(const float* __restrict__ A,
                                                 unsigned short* __restrict__ Abf) {
  const size_t total = (size_t)N_NODES * N_NODES;
  const size_t nlanes = (size_t)gridDim.x * blockDim.x;
  const size_t tid = (size_t)blockIdx.x * blockDim.x + threadIdx.x;
  // each iter consumes 8*nlanes floats; lane handles floats [base+4t, base+4t+4) and +4*nlanes
  for (size_t base = 0; base < total; base += 8 * nlanes) {
    size_t i0 = base + 4 * tid;
    size_t i1 = base + 4 * nlanes + 4 * tid;
    float4 v0 = *(const float4*)(A + i0);
    float4 v1 = *(const float4*)(A + i1);
    uint2 o0, o1;
    o0.x = f2bf(v0.x) | ((unsigned)f2bf(v0.y) << 16);
    o0.y = f2bf(v0.z) | ((unsigned)f2bf(v0.w) << 16);
    o1.x = f2bf(v1.x) | ((unsigned)f2bf(v1.y) << 16);
    o1.y = f2bf(v1.z) | ((unsigned)f2bf(v1.w) << 16);
    *(uint2*)(Abf + i0) = o0;
    *(uint2*)(Abf + i1) = o1;
  }
}

// ---------------- pre: mobius_matvec + gamma -> G^T bf16 [48][N] ----------------
// cols 0..31 = gamma*XW, col 32 = gamma-1, col 33 = 1 (rowsum->alpha), 34..47 = 0
__device__ inline void pre_math(const float* __restrict__ Wl, const float x[DIM],
                                unsigned short* __restrict__ GT, int n) {
  float xn2 = 0.f;
#pragma unroll
  for (int i = 0; i < DIM; i++) xn2 += x[i] * x[i];
  float xn = sqrtf(fmaxf(xn2, 1e-30f));
  float mx[DIM];
#pragma unroll
  for (int j = 0; j < DIM; j++) mx[j] = 0.f;
  for (int i = 0; i < DIM; i++) {
    float xi = x[i];
#pragma unroll
    for (int j = 0; j < DIM; j++) mx[j] = fmaf(xi, Wl[i * DIM + j], mx[j]);
  }
  float mxn2 = 0.f;
#pragma unroll
  for (int j = 0; j < DIM; j++) mxn2 += mx[j] * mx[j];
  float mxn = sqrtf(fmaxf(mxn2, 1e-30f));
  float t = tanhf(mxn / xn * artanh_pos(xn));
  float sc = t / mxn;
  float xw[DIM];
  float x2n = 0.f;
#pragma unroll
  for (int j = 0; j < DIM; j++) { xw[j] = sc * mx[j]; x2n += xw[j] * xw[j]; }
  float gamma = 2.0f / fmaxf(1.0f - x2n, 1e-15f);
#pragma unroll
  for (int c = 0; c < DIM; c++) GT[(size_t)c * N_NODES + n] = f2bf(gamma * xw[c]);
  GT[(size_t)DIM * N_NODES + n] = f2bf(gamma - 1.0f);
  GT[(size_t)(DIM + 1) * N_NODES + n] = f2bf(1.0f);
#pragma unroll
  for (int c = DIM + 2; c < 48; c++) GT[(size_t)c * N_NODES + n] = 0;
}

__global__ void k_pre1(const float* __restrict__ X, const float* __restrict__ W,
                       unsigned short* __restrict__ GT) {
  __shared__ float Wl[DIM * DIM];
  for (int i = threadIdx.x; i < DIM * DIM; i += blockDim.x) Wl[i] = W[i];
  __syncthreads();
  const int n = blockIdx.x * blockDim.x + threadIdx.x;
  float x[DIM];
#pragma unroll
  for (int i = 0; i < DIM; i += 4) {
    float4 v = *(const float4*)(X + (size_t)n * DIM + i);
    x[i] = v.x; x[i + 1] = v.y; x[i + 2] = v.z; x[i + 3] = v.w;
  }
  pre_math(Wl, x, GT, n);
}

// ---------------- post math: reads reduced C [N][36] ----------------
__device__ inline void post_math(const float* __restrict__ Cred, int n, float xo[DIM]) {
  float acc[36];
  const float4* p = (const float4*)(Cred + (size_t)n * NCOLC);
#pragma unroll
  for (int q = 0; q < 9; q++) {
    float4 v = p[q];
    acc[q * 4 + 0] = v.x; acc[q * 4 + 1] = v.y;
    acc[q * 4 + 2] = v.z; acc[q * 4 + 3] = v.w;
  }
  float denom = acc[32];
  float alpha = acc[33];
  denom = (denom >= 0.f) ? fmaxf(denom, 1e-10f) : fminf(denom, -1e-10f);
  float inv = 1.0f / denom;
  float v[DIM];
  float vn2 = 0.f;
#pragma unroll
  for (int c = 0; c < DIM; c++) { v[c] = acc[c] * inv; vn2 += v[c] * v[c]; }
  float vn = sqrtf(fmaxf(vn2, 1e-30f));
  float un = alpha * 0.5f * artanh_pos(vn);
  float su = un / vn;
  float r[DIM];
  float rn2 = 0.f;
#pragma unroll
  for (int c = 0; c < DIM; c++) { r[c] = fmaxf(su * v[c], 0.f); rn2 += r[c] * r[c]; }
  float rn = sqrtf(fmaxf(rn2, 1e-30f));
  float so = tanhf(rn) / rn;
#pragma unroll
  for (int c = 0; c < DIM; c++) xo[c] = so * r[c];
}

__global__ void k_postpre(const float* __restrict__ Cred, const float* __restrict__ W,
                          unsigned short* __restrict__ GT) {
  __shared__ float Wl[DIM * DIM];
  for (int i = threadIdx.x; i < DIM * DIM; i += blockDim.x) Wl[i] = W[i];
  __syncthreads();
  const int n = blockIdx.x * blockDim.x + threadIdx.x;
  float x[DIM];
  post_math(Cred, n, x);
  pre_math(Wl, x, GT, n);
}

__global__ void k_postlogits(const float* __restrict__ Cred, const float* __restrict__ Wl_g,
                             const float* __restrict__ B_g, unsigned short* __restrict__ LT) {
  __shared__ float Wc[DIM * NCLS];
  __shared__ float Bc[NCLS * DIM];
  __shared__ float an_s[NCLS], lam_s[NCLS], b2_s[NCLS];
  for (int i = threadIdx.x; i < DIM * NCLS; i += blockDim.x) { Wc[i] = Wl_g[i]; Bc[i] = B_g[i]; }
  __syncthreads();
  if (threadIdx.x < NCLS) {
    int c = threadIdx.x;
    float b2 = 0.f, w2 = 0.f;
    for (int d = 0; d < DIM; d++) {
      b2 += Bc[c * DIM + d] * Bc[c * DIM + d];
      w2 += Wc[d * NCLS + c] * Wc[d * NCLS + c];
    }
    b2_s[c] = b2;
    an_s[c] = fmaxf(sqrtf(w2), 1e-10f);
    lam_s[c] = 2.0f / fmaxf(1.0f - b2, 1e-15f);
  }
  __syncthreads();
  const int n = blockIdx.x * blockDim.x + threadIdx.x;
  float x[DIM];
  post_math(Cred, n, x);
  float y2 = 0.f;
#pragma unroll
  for (int i = 0; i < DIM; i++) y2 += x[i] * x[i];
  for (int c = 0; c < NCLS; c++) {
    float b2 = b2_s[c];
    float bx = 0.f;
    for (int d = 0; d < DIM; d++) bx += Bc[c * DIM + d] * x[d];
    float xy = -bx;
    float f1 = 1.0f + 2.0f * xy + y2;
    float f2 = 1.0f - b2;
    float den = fmaxf(1.0f + 2.0f * xy + b2 * y2, 1e-15f);
    float invden = 1.0f / den;
    float zn2 = 0.f, za = 0.f;
    for (int d = 0; d < DIM; d++) {
      float z = (f1 * (-Bc[c * DIM + d]) + f2 * x[d]) * invden;
      zn2 += z * z;
      za += z * Wc[d * NCLS + c];
    }
    float zn = fmaxf(sqrtf(fmaxf(zn2, 1e-30f)), 1e-10f);
    float dist = asinhf(2.0f * za / ((1.0f - zn * zn) * an_s[c]));
    LT[(size_t)c * N_NODES + n] = f2bf(lam_s[c] * an_s[c] * dist);
  }
}

// ---------------- MFMA matmul (bf16 A, L3-warm): direct per-lane frag loads ----------------
template <int NF>
__global__ __launch_bounds__(256) void k_mm(const unsigned short* __restrict__ A,
                                            const unsigned short* __restrict__ BT,
                                            float* __restrict__ Cpart) {
  const int lane = threadIdx.x & 63;
  const int wid = threadIdx.x >> 6;
  const int r0 = blockIdx.x * 128 + wid * 32;
  const int k0 = blockIdx.y * KSEG;
  const int lr = lane & 15;
  const int lk = (lane >> 4) * 8;
  f32x4 acc[2][NF];
#pragma unroll
  for (int m = 0; m < 2; m++)
#pragma unroll
    for (int nf = 0; nf < NF; nf++) acc[m][nf] = (f32x4){0.f, 0.f, 0.f, 0.f};
  const unsigned short* pa0 = A + (size_t)(r0 + lr) * N_NODES + k0 + lk;
  const unsigned short* pa1 = pa0 + (size_t)16 * N_NODES;
  const unsigned short* pb[NF];
#pragma unroll
  for (int nf = 0; nf < NF; nf++) pb[nf] = BT + (size_t)(nf * 16 + lr) * N_NODES + k0 + lk;
#pragma unroll 4
  for (int kk = 0; kk < KSEG; kk += 32) {
    bf16x8 a0 = *(const bf16x8*)(pa0 + kk);
    bf16x8 a1 = *(const bf16x8*)(pa1 + kk);
#pragma unroll
    for (int nf = 0; nf < NF; nf++) {
      bf16x8 b = *(const bf16x8*)(pb[nf] + kk);
      acc[0][nf] = __builtin_amdgcn_mfma_f32_16x16x32_bf16(a0, b, acc[0][nf], 0, 0, 0);
      acc[1][nf] = __builtin_amdgcn_mfma_f32_16x16x32_bf16(a1, b, acc[1][nf], 0, 0, 0);
    }
  }
  const int NCOL = (NF == 3) ? NCOLC : NF * 16;
  float* Cb = Cpart + (size_t)blockIdx.y * N_NODES * NCOL;
#pragma unroll
  for (int m = 0; m < 2; m++)
#pragma unroll
    for (int nf = 0; nf < NF; nf++) {
      if (NF == 3 && nf == 2 && lr >= 4) continue;  // cols 36..47 never read
#pragma unroll
      for (int j = 0; j < 4; j++) {
        int row = r0 + m * 16 + (lane >> 4) * 4 + j;
        int col = nf * 16 + lr;
        Cb[(size_t)row * NCOL + col] = acc[m][nf][j];
      }
    }
}

// ---------------- splitK reduce (contiguous) ----------------
template <int TOTAL>
__global__ void k_red(const float* __restrict__ part, float* __restrict__ outb) {
  int i = blockIdx.x * blockDim.x + threadIdx.x;
  if (i < TOTAL) {
    float s = 0.f;
#pragma unroll
    for (int q = 0; q < SPLITK; q++) s += part[(size_t)q * TOTAL + i];
    outb[i] = s;
  }
}

extern "C" void kernel_launch(void* const* d_in, const int* in_sizes, int n_in,
                              void* d_out, int out_size, void* d_ws, size_t ws_size,
                              hipStream_t stream) {
  (void)in_sizes; (void)n_in; (void)out_size; (void)ws_size;
  const float* X  = (const float*)d_in[0];
  const float* A  = (const float*)d_in[1];
  const float* W1 = (const float*)d_in[2];
  const float* W2 = (const float*)d_in[3];
  const float* WL = (const float*)d_in[4];
  const float* PK = (const float*)d_in[5];
  float* out = (float*)d_out;

  char* ws = (char*)d_ws;
  unsigned short* Abf = (unsigned short*)ws;                  // 134,217,728 B
  unsigned short* GT  = (unsigned short*)(ws + 134217728);    //     786,432 B
  float* Cpart        = (float*)(ws + 135004160);             //  18,874,368 B (SPLITK=16, 36 cols)
  float* Cred         = (float*)(ws + 153878528);             //   1,179,648 B
  unsigned short* LT  = (unsigned short*)(ws + 155058176);    //     262,144 B

  // streaming convert: the ONLY kernel that touches HBM-cold A
  k_convert<<<2048, 256, 0, stream>>>(A, Abf);

  // layer 1
  k_pre1<<<N_NODES / 64, 64, 0, stream>>>(X, W1, GT);
  k_mm<3><<<dim3(64, SPLITK), 256, 0, stream>>>(Abf, GT, Cpart);
  k_red<N_NODES * NCOLC><<<N_NODES * NCOLC / 256, 256, 0, stream>>>(Cpart, Cred);
  k_postpre<<<N_NODES / 64, 64, 0, stream>>>(Cred, W2, GT);

  // layer 2
  k_mm<3><<<dim3(64, SPLITK), 256, 0, stream>>>(Abf, GT, Cpart);
  k_red<N_NODES * NCOLC><<<N_NODES * NCOLC / 256, 256, 0, stream>>>(Cpart, Cred);
  k_postlogits<<<N_NODES / 64, 64, 0, stream>>>(Cred, WL, PK, LT);

  // logits aggregation
  k_mm<1><<<dim3(64, SPLITK), 256, 0, stream>>>(Abf, LT, Cpart);
  k_red<N_NODES * NCLS><<<N_NODES * NCLS / 256, 256, 0, stream>>>(Cpart, out);
}

// Round 6
// 250.667 us; speedup vs baseline: 1.1605x; 1.0216x over previous
//
#include <hip/hip_runtime.h>

#define N_NODES 8192
#define DIM 32
#define NCLS 16
#define SPLITK 16
#define KSEG (N_NODES / SPLITK) /* 512 */
#define NCOLC 36                /* packed partial-C columns (cols 36..47 structurally zero) */

typedef __bf16 bf16x8 __attribute__((ext_vector_type(8)));
typedef float f32x4 __attribute__((ext_vector_type(4)));

__device__ inline unsigned short f2bf(float f) {
  unsigned u = __float_as_uint(f);
  u = u + 0x7FFFu + ((u >> 16) & 1u);  // round-to-nearest-even
  return (unsigned short)(u >> 16);
}

__device__ inline float artanh_pos(float x) {  // x >= 0, clipped like jnp reference
  x = fminf(x, 1.0f - 1e-7f);
  return 0.5f * logf((1.0f + x) / (1.0f - x));
}

// ---------------- A fp32 -> bf16 (RNE) into split-K panel layout ----------------
// Abf[s][row][512]: element (r,k) -> s=k>>9, idx = s*8192*512 + r*512 + (k&511).
// Each mm block then owns a CONTIGUOUS 128KB region -> deep DRAM page streams.
__global__ __launch_bounds__(256) void k_convert(const float* __restrict__ A,
                                                 unsigned short* __restrict__ Abf) {
  const size_t total = (size_t)N_NODES * N_NODES;
  const size_t nlanes = (size_t)gridDim.x * blockDim.x;
  const size_t tid = (size_t)blockIdx.x * blockDim.x + threadIdx.x;
  for (size_t base = 0; base < total; base += 8 * nlanes) {
    size_t i0 = base + 4 * tid;
    size_t i1 = base + 4 * nlanes + 4 * tid;
    float4 v0 = *(const float4*)(A + i0);
    float4 v1 = *(const float4*)(A + i1);
    uint2 o0, o1;
    o0.x = f2bf(v0.x) | ((unsigned)f2bf(v0.y) << 16);
    o0.y = f2bf(v0.z) | ((unsigned)f2bf(v0.w) << 16);
    o1.x = f2bf(v1.x) | ((unsigned)f2bf(v1.y) << 16);
    o1.y = f2bf(v1.z) | ((unsigned)f2bf(v1.w) << 16);
    // panelized write index (k%4==0 chunks never cross the 512 boundary)
    size_t r0 = i0 >> 13, k0 = i0 & 8191;
    size_t r1 = i1 >> 13, k1 = i1 & 8191;
    size_t o0i = (k0 >> 9) * ((size_t)N_NODES * KSEG) + r0 * KSEG + (k0 & 511);
    size_t o1i = (k1 >> 9) * ((size_t)N_NODES * KSEG) + r1 * KSEG + (k1 & 511);
    *(uint2*)(Abf + o0i) = o0;
    *(uint2*)(Abf + o1i) = o1;
  }
}

// ---------------- pre: mobius_matvec + gamma -> G^T bf16 [48][N] ----------------
// cols 0..31 = gamma*XW, col 32 = gamma-1, col 33 = 1 (rowsum->alpha), 34..47 = 0
__device__ inline void pre_math(const float* __restrict__ Wl, const float x[DIM],
                                unsigned short* __restrict__ GT, int n) {
  float xn2 = 0.f;
#pragma unroll
  for (int i = 0; i < DIM; i++) xn2 += x[i] * x[i];
  float xn = sqrtf(fmaxf(xn2, 1e-30f));
  float mx[DIM];
#pragma unroll
  for (int j = 0; j < DIM; j++) mx[j] = 0.f;
  for (int i = 0; i < DIM; i++) {
    float xi = x[i];
#pragma unroll
    for (int j = 0; j < DIM; j++) mx[j] = fmaf(xi, Wl[i * DIM + j], mx[j]);
  }
  float mxn2 = 0.f;
#pragma unroll
  for (int j = 0; j < DIM; j++) mxn2 += mx[j] * mx[j];
  float mxn = sqrtf(fmaxf(mxn2, 1e-30f));
  float t = tanhf(mxn / xn * artanh_pos(xn));
  float sc = t / mxn;
  float xw[DIM];
  float x2n = 0.f;
#pragma unroll
  for (int j = 0; j < DIM; j++) { xw[j] = sc * mx[j]; x2n += xw[j] * xw[j]; }
  float gamma = 2.0f / fmaxf(1.0f - x2n, 1e-15f);
#pragma unroll
  for (int c = 0; c < DIM; c++) GT[(size_t)c * N_NODES + n] = f2bf(gamma * xw[c]);
  GT[(size_t)DIM * N_NODES + n] = f2bf(gamma - 1.0f);
  GT[(size_t)(DIM + 1) * N_NODES + n] = f2bf(1.0f);
#pragma unroll
  for (int c = DIM + 2; c < 48; c++) GT[(size_t)c * N_NODES + n] = 0;
}

__global__ void k_pre1(const float* __restrict__ X, const float* __restrict__ W,
                       unsigned short* __restrict__ GT) {
  __shared__ float Wl[DIM * DIM];
  for (int i = threadIdx.x; i < DIM * DIM; i += blockDim.x) Wl[i] = W[i];
  __syncthreads();
  const int n = blockIdx.x * blockDim.x + threadIdx.x;
  float x[DIM];
#pragma unroll
  for (int i = 0; i < DIM; i += 4) {
    float4 v = *(const float4*)(X + (size_t)n * DIM + i);
    x[i] = v.x; x[i + 1] = v.y; x[i + 2] = v.z; x[i + 3] = v.w;
  }
  pre_math(Wl, x, GT, n);
}

// ---------------- post math: reads reduced C [N][36] ----------------
__device__ inline void post_math(const float* __restrict__ Cred, int n, float xo[DIM]) {
  float acc[36];
  const float4* p = (const float4*)(Cred + (size_t)n * NCOLC);
#pragma unroll
  for (int q = 0; q < 9; q++) {
    float4 v = p[q];
    acc[q * 4 + 0] = v.x; acc[q * 4 + 1] = v.y;
    acc[q * 4 + 2] = v.z; acc[q * 4 + 3] = v.w;
  }
  float denom = acc[32];
  float alpha = acc[33];
  denom = (denom >= 0.f) ? fmaxf(denom, 1e-10f) : fminf(denom, -1e-10f);
  float inv = 1.0f / denom;
  float v[DIM];
  float vn2 = 0.f;
#pragma unroll
  for (int c = 0; c < DIM; c++) { v[c] = acc[c] * inv; vn2 += v[c] * v[c]; }
  float vn = sqrtf(fmaxf(vn2, 1e-30f));
  float un = alpha * 0.5f * artanh_pos(vn);
  float su = un / vn;
  float r[DIM];
  float rn2 = 0.f;
#pragma unroll
  for (int c = 0; c < DIM; c++) { r[c] = fmaxf(su * v[c], 0.f); rn2 += r[c] * r[c]; }
  float rn = sqrtf(fmaxf(rn2, 1e-30f));
  float so = tanhf(rn) / rn;
#pragma unroll
  for (int c = 0; c < DIM; c++) xo[c] = so * r[c];
}

__global__ void k_postpre(const float* __restrict__ Cred, const float* __restrict__ W,
                          unsigned short* __restrict__ GT) {
  __shared__ float Wl[DIM * DIM];
  for (int i = threadIdx.x; i < DIM * DIM; i += blockDim.x) Wl[i] = W[i];
  __syncthreads();
  const int n = blockIdx.x * blockDim.x + threadIdx.x;
  float x[DIM];
  post_math(Cred, n, x);
  pre_math(Wl, x, GT, n);
}

__global__ void k_postlogits(const float* __restrict__ Cred, const float* __restrict__ Wl_g,
                             const float* __restrict__ B_g, unsigned short* __restrict__ LT) {
  __shared__ float Wc[DIM * NCLS];
  __shared__ float Bc[NCLS * DIM];
  __shared__ float an_s[NCLS], lam_s[NCLS], b2_s[NCLS];
  for (int i = threadIdx.x; i < DIM * NCLS; i += blockDim.x) { Wc[i] = Wl_g[i]; Bc[i] = B_g[i]; }
  __syncthreads();
  if (threadIdx.x < NCLS) {
    int c = threadIdx.x;
    float b2 = 0.f, w2 = 0.f;
    for (int d = 0; d < DIM; d++) {
      b2 += Bc[c * DIM + d] * Bc[c * DIM + d];
      w2 += Wc[d * NCLS + c] * Wc[d * NCLS + c];
    }
    b2_s[c] = b2;
    an_s[c] = fmaxf(sqrtf(w2), 1e-10f);
    lam_s[c] = 2.0f / fmaxf(1.0f - b2, 1e-15f);
  }
  __syncthreads();
  const int n = blockIdx.x * blockDim.x + threadIdx.x;
  float x[DIM];
  post_math(Cred, n, x);
  float y2 = 0.f;
#pragma unroll
  for (int i = 0; i < DIM; i++) y2 += x[i] * x[i];
  for (int c = 0; c < NCLS; c++) {
    float b2 = b2_s[c];
    float bx = 0.f;
    for (int d = 0; d < DIM; d++) bx += Bc[c * DIM + d] * x[d];
    float xy = -bx;
    float f1 = 1.0f + 2.0f * xy + y2;
    float f2 = 1.0f - b2;
    float den = fmaxf(1.0f + 2.0f * xy + b2 * y2, 1e-15f);
    float invden = 1.0f / den;
    float zn2 = 0.f, za = 0.f;
    for (int d = 0; d < DIM; d++) {
      float z = (f1 * (-Bc[c * DIM + d]) + f2 * x[d]) * invden;
      zn2 += z * z;
      za += z * Wc[d * NCLS + c];
    }
    float zn = fmaxf(sqrtf(fmaxf(zn2, 1e-30f)), 1e-10f);
    float dist = asinhf(2.0f * za / ((1.0f - zn * zn) * an_s[c]));
    LT[(size_t)c * N_NODES + n] = f2bf(lam_s[c] * an_s[c] * dist);
  }
}

// ---------------- MFMA matmul (bf16 A, split-K panel layout) ----------------
// Block (x,y) reads Abf panel y rows [x*128, x*128+128) -> one contiguous 128KB region.
template <int NF>
__global__ __launch_bounds__(256) void k_mm(const unsigned short* __restrict__ A,
                                            const unsigned short* __restrict__ BT,
                                            float* __restrict__ Cpart) {
  const int lane = threadIdx.x & 63;
  const int wid = threadIdx.x >> 6;
  const int r0 = blockIdx.x * 128 + wid * 32;
  const int k0 = blockIdx.y * KSEG;
  const int lr = lane & 15;
  const int lk = (lane >> 4) * 8;
  f32x4 acc[2][NF];
#pragma unroll
  for (int m = 0; m < 2; m++)
#pragma unroll
    for (int nf = 0; nf < NF; nf++) acc[m][nf] = (f32x4){0.f, 0.f, 0.f, 0.f};
  // panel base: split y, row r, 512-el contiguous row segments
  const unsigned short* pa0 =
      A + (size_t)blockIdx.y * N_NODES * KSEG + (size_t)(r0 + lr) * KSEG + lk;
  const unsigned short* pa1 = pa0 + (size_t)16 * KSEG;
  const unsigned short* pb[NF];
#pragma unroll
  for (int nf = 0; nf < NF; nf++) pb[nf] = BT + (size_t)(nf * 16 + lr) * N_NODES + k0 + lk;
#pragma unroll 4
  for (int kk = 0; kk < KSEG; kk += 32) {
    bf16x8 a0 = *(const bf16x8*)(pa0 + kk);
    bf16x8 a1 = *(const bf16x8*)(pa1 + kk);
#pragma unroll
    for (int nf = 0; nf < NF; nf++) {
      bf16x8 b = *(const bf16x8*)(pb[nf] + kk);
      acc[0][nf] = __builtin_amdgcn_mfma_f32_16x16x32_bf16(a0, b, acc[0][nf], 0, 0, 0);
      acc[1][nf] = __builtin_amdgcn_mfma_f32_16x16x32_bf16(a1, b, acc[1][nf], 0, 0, 0);
    }
  }
  const int NCOL = (NF == 3) ? NCOLC : NF * 16;
  float* Cb = Cpart + (size_t)blockIdx.y * N_NODES * NCOL;
#pragma unroll
  for (int m = 0; m < 2; m++)
#pragma unroll
    for (int nf = 0; nf < NF; nf++) {
      if (NF == 3 && nf == 2 && lr >= 4) continue;  // cols 36..47 never read
#pragma unroll
      for (int j = 0; j < 4; j++) {
        int row = r0 + m * 16 + (lane >> 4) * 4 + j;
        int col = nf * 16 + lr;
        Cb[(size_t)row * NCOL + col] = acc[m][nf][j];
      }
    }
}

// ---------------- splitK reduce (contiguous) ----------------
template <int TOTAL>
__global__ void k_red(const float* __restrict__ part, float* __restrict__ outb) {
  int i = blockIdx.x * blockDim.x + threadIdx.x;
  if (i < TOTAL) {
    float s = 0.f;
#pragma unroll
    for (int q = 0; q < SPLITK; q++) s += part[(size_t)q * TOTAL + i];
    outb[i] = s;
  }
}

extern "C" void kernel_launch(void* const* d_in, const int* in_sizes, int n_in,
                              void* d_out, int out_size, void* d_ws, size_t ws_size,
                              hipStream_t stream) {
  (void)in_sizes; (void)n_in; (void)out_size; (void)ws_size;
  const float* X  = (const float*)d_in[0];
  const float* A  = (const float*)d_in[1];
  const float* W1 = (const float*)d_in[2];
  const float* W2 = (const float*)d_in[3];
  const float* WL = (const float*)d_in[4];
  const float* PK = (const float*)d_in[5];
  float* out = (float*)d_out;

  char* ws = (char*)d_ws;
  unsigned short* Abf = (unsigned short*)ws;                  // 134,217,728 B
  unsigned short* GT  = (unsigned short*)(ws + 134217728);    //     786,432 B
  float* Cpart        = (float*)(ws + 135004160);             //  18,874,368 B (SPLITK=16, 36 cols)
  float* Cred         = (float*)(ws + 153878528);             //   1,179,648 B
  unsigned short* LT  = (unsigned short*)(ws + 155058176);    //     262,144 B

  // streaming convert: the ONLY kernel that touches HBM-cold A (panelized output)
  k_convert<<<2048, 256, 0, stream>>>(A, Abf);

  // layer 1
  k_pre1<<<N_NODES / 64, 64, 0, stream>>>(X, W1, GT);
  k_mm<3><<<dim3(64, SPLITK), 256, 0, stream>>>(Abf, GT, Cpart);
  k_red<N_NODES * NCOLC><<<N_NODES * NCOLC / 256, 256, 0, stream>>>(Cpart, Cred);
  k_postpre<<<N_NODES / 64, 64, 0, stream>>>(Cred, W2, GT);

  // layer 2
  k_mm<3><<<dim3(64, SPLITK), 256, 0, stream>>>(Abf, GT, Cpart);
  k_red<N_NODES * NCOLC><<<N_NODES * NCOLC / 256, 256, 0, stream>>>(Cpart, Cred);
  k_postlogits<<<N_NODES / 64, 64, 0, stream>>>(Cred, WL, PK, LT);

  // logits aggregation
  k_mm<1><<<dim3(64, SPLITK), 256, 0, stream>>>(Abf, LT, Cpart);
  k_red<N_NODES * NCLS><<<N_NODES * NCLS / 256, 256, 0, stream>>>(Cpart, out);
}